// Round 7
// baseline (329.992 us; speedup 1.0000x reference)
//
#include <hip/hip_runtime.h>
#include <math.h>

// B=4096, K=128, D=256.
// out[b,d] = sqrt(1-e) * sum_k p_k * (x - a*c)/var,  var = 1 + e*(s^2-1)
// lp_k = -0.5*S1 - 128*ln2*S2 + ln w_k  (k-uniform const dropped)
//   S1 = sum_d diff^2/var, S2 = sum_d log2(var)
// Packed 2xf32 math (f2 lanes = 2 batch rows), 4-way combined division
// (1 rcp / 4 d-tuples), 1 log per 16 d.
// R7: R6 skeleton (512 thr, G=4, grid=1024, 32 waves/CU) + explicit
// next-iteration register prefetch of global table loads (R6 showed 43%
// idle is dependency stalls, not occupancy) + k-pair-packed pass-2 table
// (dwordx4, half the VMEM instr) + dead code removed.

constexpr int Kc = 128;
constexpr int Dc = 256;
constexpr int G  = 4;   // batch rows per block (2 f2 pairs)

typedef float f2 __attribute__((ext_vector_type(2)));
typedef float f4 __attribute__((ext_vector_type(4)));

static __device__ __forceinline__ f2 fma2(f2 a, f2 b, f2 c) {
    return __builtin_elementwise_fma(a, b, c);
}
static __device__ __forceinline__ f2 splat2(float s) { return (f2){s, s}; }
static __device__ __forceinline__ f2 rcp2(f2 a) {
    return (f2){__builtin_amdgcn_rcpf(a[0]), __builtin_amdgcn_rcpf(a[1])};
}

// prep: CA8[(d>>2)][k][8] = {c0..c3, A0..A3}   (pass-1, d-transposed)
//       PT[(k>>1)][d]     = {c_k, A_k, c_k+1, A_k+1} (pass-2, k-paired)
__global__ void prep_kernel(const float* __restrict__ centers,
                            const float* __restrict__ stds,
                            float* __restrict__ CA8, float* __restrict__ PT) {
    int idx = blockIdx.x * blockDim.x + threadIdx.x;   // k*Dc + d
    if (idx >= Kc * Dc) return;
    int k = idx >> 8;
    int d = idx & (Dc - 1);
    float c = centers[idx];
    float s = stds[idx];
    float A = s * s - 1.0f;
    int o = (d >> 2) * (Kc * 8) + k * 8 + (d & 3);
    CA8[o]     = c;
    CA8[o + 4] = A;
    int o2 = ((((k >> 1) * Dc) + d) << 2) + ((k & 1) << 1);
    PT[o2]     = c;
    PT[o2 + 1] = A;
}

__global__ __launch_bounds__(512, 8) void score_kernel(
    const float* __restrict__ x, const float* __restrict__ t,
    const float* __restrict__ weights,
    const float* __restrict__ CA8, const float* __restrict__ PT,
    float* __restrict__ out)
{
    const int b0  = blockIdx.x * G;
    const int tid = threadIdx.x;

    __shared__ __align__(16) f4 xT[Dc];        // xT[d] = {x_g0..x_g3}   4 KB
    __shared__ float part1[G][4][Kc];          //                        8 KB
    __shared__ float partL[G][4][Kc];          //                        8 KB
    __shared__ __align__(16) f4 peT[Kc];       // softmax numerators     2 KB
    __shared__ __align__(16) f4 Opart[Dc];     // pass-2 upper-half O    4 KB
    __shared__ float wmax[G][2];
    __shared__ float wsum[G][2];

    // per-row scalars (block-uniform)
    float e[G], na[G], sg[G];
    #pragma unroll
    for (int g = 0; g < G; ++g) {
        float tt = t[b0 + g];
        float Bt = fmaf(9.95f * tt, tt, 0.1f * tt);
        float ee = __expf(-Bt);
        e[g]  = ee;
        na[g] = -sqrtf(ee);
        sg[g] = sqrtf(1.0f - ee);
    }
    f2 e2[2]  = {{e[0], e[1]}, {e[2], e[3]}};
    f2 na2[2] = {{na[0], na[1]}, {na[2], na[3]}};
    const f2 one2 = {1.0f, 1.0f};

    if (tid < Dc) {
        f4 xv;
        #pragma unroll
        for (int g = 0; g < G; ++g) xv[g] = x[(b0 + g) * Dc + tid];
        xT[tid] = xv;
    }
    __syncthreads();

    // ---------------- pass 1: thread = (k, quarter-of-D), 64 d each ----------------
    const int kk  = tid & (Kc - 1);
    const int qtr = tid >> 7;                  // 0..3

    const f4* xTv = (const f4*)(&xT[0]);
    const float* base0 = CA8 + (qtr * 16 * Kc + kk) * 8;   // +Kc*8 floats per quad

    f2 acc1[2] = {{0.f, 0.f}, {0.f, 0.f}};
    float accL[G] = {0.f, 0.f, 0.f, 0.f};
    f2 prod[2] = {{1.f, 1.f}, {1.f, 1.f}};

    // prefetch quad 0
    f4 c4n = *(const f4*)base0;
    f4 A4n = *(const f4*)(base0 + 4);

    #pragma unroll 4
    for (int qq = 0; qq < 16; ++qq) {
        f4 c4 = c4n, A4 = A4n;
        if (qq < 15) {                         // prefetch next quad
            const float* bn = base0 + (qq + 1) * (Kc * 8);
            c4n = *(const f4*)bn;
            A4n = *(const f4*)(bn + 4);
        }
        const int d0 = qtr * 64 + qq * 4;
        f4 xv0 = xTv[d0 + 0];                  // LDS b128 broadcast (d uniform)
        f4 xv1 = xTv[d0 + 1];
        f4 xv2 = xTv[d0 + 2];
        f4 xv3 = xTv[d0 + 3];
        #pragma unroll
        for (int p = 0; p < 2; ++p) {
            f2 ep = e2[p], nap = na2[p];
            f2 x0 = {xv0[2*p], xv0[2*p+1]};
            f2 x1 = {xv1[2*p], xv1[2*p+1]};
            f2 x2 = {xv2[2*p], xv2[2*p+1]};
            f2 x3 = {xv3[2*p], xv3[2*p+1]};
            f2 v0 = fma2(ep, splat2(A4[0]), one2);   // var in [0.25,1]
            f2 v1 = fma2(ep, splat2(A4[1]), one2);
            f2 v2 = fma2(ep, splat2(A4[2]), one2);
            f2 v3 = fma2(ep, splat2(A4[3]), one2);
            f2 f0 = fma2(nap, splat2(c4[0]), x0);
            f2 f1 = fma2(nap, splat2(c4[1]), x1);
            f2 f2_ = fma2(nap, splat2(c4[2]), x2);
            f2 f3 = fma2(nap, splat2(c4[3]), x3);
            f2 s0 = f0 * f0, s1 = f1 * f1, s2 = f2_ * f2_, s3 = f3 * f3;
            f2 d01 = v0 * v1, d23 = v2 * v3;
            f2 n01 = fma2(s1, v0, s0 * v1);
            f2 n23 = fma2(s3, v2, s2 * v3);
            f2 den = d01 * d23;                      // >= 0.25^4
            f2 num = fma2(n23, d01, n01 * d23);
            acc1[p] = fma2(num, rcp2(den), acc1[p]);
            prod[p] = prod[p] * den;
        }
        if ((qq & 3) == 3) {                   // prod >= 0.25^16 > 2e-10: safe
            accL[0] += __log2f(prod[0][0]);
            accL[1] += __log2f(prod[0][1]);
            accL[2] += __log2f(prod[1][0]);
            accL[3] += __log2f(prod[1][1]);
            prod[0] = one2; prod[1] = one2;
        }
    }
    #pragma unroll
    for (int p = 0; p < 2; ++p) {
        part1[2*p  ][qtr][kk] = acc1[p][0];
        part1[2*p+1][qtr][kk] = acc1[p][1];
    }
    #pragma unroll
    for (int g = 0; g < G; ++g)
        partL[g][qtr][kk] = accL[g];
    __syncthreads();

    // ---------------- softmax over k (threads < K, 2 full waves) ----------------
    float lpv[G];
    if (tid < Kc) {
        float lw = __logf(weights[tid]);
        #pragma unroll
        for (int g = 0; g < G; ++g) {
            float S1 = (part1[g][0][tid] + part1[g][1][tid])
                     + (part1[g][2][tid] + part1[g][3][tid]);
            float S2 = (partL[g][0][tid] + partL[g][1][tid])
                     + (partL[g][2][tid] + partL[g][3][tid]);
            lpv[g] = fmaf(-0.5f, S1, fmaf(-88.72283911167299f, S2, lw)); // 128*ln2
            float m = lpv[g];
            #pragma unroll
            for (int off = 32; off > 0; off >>= 1)
                m = fmaxf(m, __shfl_xor(m, off, 64));
            if ((tid & 63) == 0) wmax[g][tid >> 6] = m;
        }
    }
    __syncthreads();
    if (tid < Kc) {
        f4 pe4;
        #pragma unroll
        for (int g = 0; g < G; ++g) {
            float m  = fmaxf(wmax[g][0], wmax[g][1]);
            float pe = __expf(lpv[g] - m);
            pe4[g] = pe;
            float s = pe;
            #pragma unroll
            for (int off = 32; off > 0; off >>= 1)
                s += __shfl_xor(s, off, 64);
            if ((tid & 63) == 0) wsum[g][tid >> 6] = s;
        }
        peT[tid] = pe4;                        // unnormalized; 1/Z in epilogue
    }
    __syncthreads();

    // ---------------- pass 2: thread = (d, half-of-K), 64 k each ----------------
    const int dd = tid & (Dc - 1);
    const int kh = tid >> 8;                   // 0..1

    f4 xv = xT[dd];
    f2 xp[2] = {{xv[0], xv[1]}, {xv[2], xv[3]}};
    f2 O[2] = {{0.f, 0.f}, {0.f, 0.f}};
    const f4* PTv = (const f4*)PT;             // [(k>>1)*Dc + d]
    const int j0 = kh * 32;                    // first k-pair index

    // prefetch first 2 k-pairs (4 k)
    f4 abn = PTv[(j0 + 0) * Dc + dd];
    f4 cdn = PTv[(j0 + 1) * Dc + dd];

    #pragma unroll 4
    for (int it = 0; it < 16; ++it) {
        f4 ab = abn, cd = cdn;                 // {c,A} for k0..k0+3
        if (it < 15) {
            abn = PTv[(j0 + 2 * it + 2) * Dc + dd];
            cdn = PTv[(j0 + 2 * it + 3) * Dc + dd];
        }
        const int k0 = (j0 + 2 * it) * 2;
        f4 peA = peT[k0 + 0];                  // LDS b128 broadcast
        f4 peB = peT[k0 + 1];
        f4 peC = peT[k0 + 2];
        f4 peD = peT[k0 + 3];
        #pragma unroll
        for (int p = 0; p < 2; ++p) {
            f2 ep = e2[p], nap = na2[p];
            f2 v0 = fma2(ep, splat2(ab[1]), one2);
            f2 v1 = fma2(ep, splat2(ab[3]), one2);
            f2 v2 = fma2(ep, splat2(cd[1]), one2);
            f2 v3 = fma2(ep, splat2(cd[3]), one2);
            f2 f0 = fma2(nap, splat2(ab[0]), xp[p]);
            f2 f1 = fma2(nap, splat2(ab[2]), xp[p]);
            f2 f2_ = fma2(nap, splat2(cd[0]), xp[p]);
            f2 f3 = fma2(nap, splat2(cd[2]), xp[p]);
            f2 u0 = (f2){peA[2*p], peA[2*p+1]} * f0;
            f2 u1 = (f2){peB[2*p], peB[2*p+1]} * f1;
            f2 u2 = (f2){peC[2*p], peC[2*p+1]} * f2_;
            f2 u3 = (f2){peD[2*p], peD[2*p+1]} * f3;
            f2 d01 = v0 * v1, d23 = v2 * v3;
            f2 n01 = fma2(u1, v0, u0 * v1);
            f2 n23 = fma2(u3, v2, u2 * v3);
            f2 den = d01 * d23;
            f2 num = fma2(n23, d01, n01 * d23);
            O[p] = fma2(num, rcp2(den), O[p]);
        }
    }

    if (kh == 1)
        Opart[dd] = (f4){O[0][0], O[0][1], O[1][0], O[1][1]};
    __syncthreads();

    if (tid < Dc) {
        f4 Ou = Opart[tid];
        #pragma unroll
        for (int p = 0; p < 2; ++p) {
            #pragma unroll
            for (int j = 0; j < 2; ++j) {
                int g = 2 * p + j;
                float Z = wsum[g][0] + wsum[g][1];
                float Osum = O[p][j] + Ou[2 * p + j];
                out[(b0 + g) * Dc + tid] = sg[g] * __builtin_amdgcn_rcpf(Z) * Osum;
            }
        }
    }
}

extern "C" void kernel_launch(void* const* d_in, const int* in_sizes, int n_in,
                              void* d_out, int out_size, void* d_ws, size_t ws_size,
                              hipStream_t stream) {
    const float* x       = (const float*)d_in[0];
    const float* t       = (const float*)d_in[1];
    const float* centers = (const float*)d_in[2];
    const float* stds    = (const float*)d_in[3];
    const float* weights = (const float*)d_in[4];
    float* outp = (float*)d_out;

    float* CA8 = (float*)d_ws;                    // [D/4][K][8]       (256 KB)
    float* PT  = CA8 + Kc * Dc * 2;               // [K/2][D]{c,A,c,A} (256 KB)

    const int B = in_sizes[1];                    // 4096

    prep_kernel<<<(Kc * Dc + 255) / 256, 256, 0, stream>>>(centers, stds, CA8, PT);
    score_kernel<<<B / G, 512, 0, stream>>>(x, t, weights, CA8, PT, outp);
}

// Round 8
// 110.384 us; speedup vs baseline: 2.9895x; 2.9895x over previous
//
#include <hip/hip_runtime.h>
#include <math.h>

// B=4096, K=128, D=256.
// out[b,d] = sqrt(1-e) * sum_k p_k * (x - a*c)/var,  var = 1 + e*(s^2-1)
// lp_k = -0.5*S1 - 128*ln2*S2 + ln w_k  (k-uniform const dropped)
// Packed 2xf32 math (f2 lanes = 2 batch rows), 4-way combined division,
// 1 log per 16 d. 512 thr, G=4, grid=1024.
// R8: pass-1 x values come from a pre-transposed global table via WAVE-UNIFORM
// scalar loads (constant cache) instead of LDS broadcasts -- R6/R3 parity at
// 2x occupancy showed the stall is a CU-shared pipe (LDS broadcast reads),
// not wave count. No manual prefetch (R7's spilled: 814 MB scratch WRITE).

constexpr int Kc = 128;
constexpr int Dc = 256;
constexpr int G  = 4;   // batch rows per block (2 f2 pairs)

typedef float f2 __attribute__((ext_vector_type(2)));
typedef float f4 __attribute__((ext_vector_type(4)));

static __device__ __forceinline__ f2 fma2(f2 a, f2 b, f2 c) {
    return __builtin_elementwise_fma(a, b, c);
}
static __device__ __forceinline__ f2 splat2(float s) { return (f2){s, s}; }
static __device__ __forceinline__ f2 rcp2(f2 a) {
    return (f2){__builtin_amdgcn_rcpf(a[0]), __builtin_amdgcn_rcpf(a[1])};
}

// prep tables: CA8[(d>>2)][k][8] = {c0..c3, A0..A3}   (pass-1, d-transposed)
//              PT[(k>>1)][d]     = {c_k,A_k,c_k+1,A_k+1} (pass-2, k-paired)
__global__ void prep_kernel(const float* __restrict__ centers,
                            const float* __restrict__ stds,
                            float* __restrict__ CA8, float* __restrict__ PT) {
    int idx = blockIdx.x * blockDim.x + threadIdx.x;   // k*Dc + d
    if (idx >= Kc * Dc) return;
    int k = idx >> 8;
    int d = idx & (Dc - 1);
    float c = centers[idx];
    float s = stds[idx];
    float A = s * s - 1.0f;
    int o = (d >> 2) * (Kc * 8) + k * 8 + (d & 3);
    CA8[o]     = c;
    CA8[o + 4] = A;
    int o2 = ((((k >> 1) * Dc) + d) << 2) + ((k & 1) << 1);
    PT[o2]     = c;
    PT[o2 + 1] = A;
}

// prep x: xt4[b4*Dc + d] = {x[4b4+0][d], .., x[4b4+3][d]}  (4-row transpose)
__global__ void prep_x(const float* __restrict__ x, f4* __restrict__ xt4, int n4) {
    int idx = blockIdx.x * blockDim.x + threadIdx.x;   // b4*Dc + d
    if (idx >= n4) return;
    int b4 = idx >> 8;
    int d  = idx & (Dc - 1);
    f4 v;
    #pragma unroll
    for (int g = 0; g < G; ++g)
        v[g] = x[(b4 * G + g) * Dc + d];
    xt4[idx] = v;
}

__global__ __launch_bounds__(512, 8) void score_kernel(
    const f4* __restrict__ xt4, const float* __restrict__ t,
    const float* __restrict__ weights,
    const float* __restrict__ CA8, const float* __restrict__ PT,
    float* __restrict__ out)
{
    const int b0  = blockIdx.x * G;
    const int tid = threadIdx.x;

    __shared__ float part1[G][4][Kc];          // pass-1 S1 partials     8 KB
    __shared__ float partL[G][4][Kc];          // pass-1 S2 partials     8 KB
    __shared__ __align__(16) f4 peT[Kc];       // softmax numerators     2 KB
    __shared__ __align__(16) f4 Opart[Dc];     // pass-2 upper-half O    4 KB
    __shared__ float wmax[G][2];
    __shared__ float wsum[G][2];

    // per-row scalars (block-uniform)
    float e[G], na[G], sg[G];
    #pragma unroll
    for (int g = 0; g < G; ++g) {
        float tt = t[b0 + g];
        float Bt = fmaf(9.95f * tt, tt, 0.1f * tt);
        float ee = __expf(-Bt);
        e[g]  = ee;
        na[g] = -sqrtf(ee);
        sg[g] = sqrtf(1.0f - ee);
    }
    f2 e2[2]  = {{e[0], e[1]}, {e[2], e[3]}};
    f2 na2[2] = {{na[0], na[1]}, {na[2], na[3]}};
    const f2 one2 = {1.0f, 1.0f};

    // ---------------- pass 1: thread = (k, quarter-of-D), 64 d each ----------------
    const int kk  = tid & (Kc - 1);
    const int qtr = __builtin_amdgcn_readfirstlane(tid >> 7);  // wave-uniform 0..3

    const f4* xrow = xt4 + (size_t)blockIdx.x * Dc;  // uniform base; [d] -> 4 g's

    f2 acc1[2] = {{0.f, 0.f}, {0.f, 0.f}};
    float accL[G] = {0.f, 0.f, 0.f, 0.f};

    for (int grp = 0; grp < 4; ++grp) {        // 4 groups x 4 quads x 4 d = 64 d
        f2 prod[2] = {{1.f, 1.f}, {1.f, 1.f}};
        #pragma unroll
        for (int q = 0; q < 4; ++q) {
            const int dq = qtr * 16 + grp * 4 + q;       // quad index (uniform)
            const float* base = CA8 + ((size_t)dq * Kc + kk) * 8;
            f4 c4 = *(const f4*)base;          // dwordx4, coalesced over kk
            f4 A4 = *(const f4*)(base + 4);    // same addr + imm 16
            const int d0 = dq * 4;
            f4 xv0 = xrow[d0 + 0];             // wave-uniform -> s_load (SMEM)
            f4 xv1 = xrow[d0 + 1];
            f4 xv2 = xrow[d0 + 2];
            f4 xv3 = xrow[d0 + 3];
            #pragma unroll
            for (int p = 0; p < 2; ++p) {
                f2 ep = e2[p], nap = na2[p];
                f2 x0 = {xv0[2*p], xv0[2*p+1]};
                f2 x1 = {xv1[2*p], xv1[2*p+1]};
                f2 x2 = {xv2[2*p], xv2[2*p+1]};
                f2 x3 = {xv3[2*p], xv3[2*p+1]};
                f2 v0 = fma2(ep, splat2(A4[0]), one2);   // var in [0.25,1]
                f2 v1 = fma2(ep, splat2(A4[1]), one2);
                f2 v2 = fma2(ep, splat2(A4[2]), one2);
                f2 v3 = fma2(ep, splat2(A4[3]), one2);
                f2 f0 = fma2(nap, splat2(c4[0]), x0);
                f2 f1 = fma2(nap, splat2(c4[1]), x1);
                f2 f2_ = fma2(nap, splat2(c4[2]), x2);
                f2 f3 = fma2(nap, splat2(c4[3]), x3);
                f2 s0 = f0 * f0, s1 = f1 * f1, s2 = f2_ * f2_, s3 = f3 * f3;
                f2 d01 = v0 * v1, d23 = v2 * v3;
                f2 n01 = fma2(s1, v0, s0 * v1);
                f2 n23 = fma2(s3, v2, s2 * v3);
                f2 den = d01 * d23;                      // >= 0.25^4
                f2 num = fma2(n23, d01, n01 * d23);
                acc1[p] = fma2(num, rcp2(den), acc1[p]);
                prod[p] = prod[p] * den;
            }
        }
        accL[0] += __log2f(prod[0][0]);        // prod >= 0.25^16: safe
        accL[1] += __log2f(prod[0][1]);
        accL[2] += __log2f(prod[1][0]);
        accL[3] += __log2f(prod[1][1]);
    }
    #pragma unroll
    for (int p = 0; p < 2; ++p) {
        part1[2*p  ][qtr][kk] = acc1[p][0];
        part1[2*p+1][qtr][kk] = acc1[p][1];
    }
    #pragma unroll
    for (int g = 0; g < G; ++g)
        partL[g][qtr][kk] = accL[g];
    __syncthreads();

    // ---------------- softmax over k (threads < K, 2 full waves) ----------------
    float lpv[G];
    if (tid < Kc) {
        float lw = __logf(weights[tid]);
        #pragma unroll
        for (int g = 0; g < G; ++g) {
            float S1 = (part1[g][0][tid] + part1[g][1][tid])
                     + (part1[g][2][tid] + part1[g][3][tid]);
            float S2 = (partL[g][0][tid] + partL[g][1][tid])
                     + (partL[g][2][tid] + partL[g][3][tid]);
            lpv[g] = fmaf(-0.5f, S1, fmaf(-88.72283911167299f, S2, lw)); // 128*ln2
            float m = lpv[g];
            #pragma unroll
            for (int off = 32; off > 0; off >>= 1)
                m = fmaxf(m, __shfl_xor(m, off, 64));
            if ((tid & 63) == 0) wmax[g][tid >> 6] = m;
        }
    }
    __syncthreads();
    if (tid < Kc) {
        f4 pe4;
        #pragma unroll
        for (int g = 0; g < G; ++g) {
            float m  = fmaxf(wmax[g][0], wmax[g][1]);
            float pe = __expf(lpv[g] - m);
            pe4[g] = pe;
            float s = pe;
            #pragma unroll
            for (int off = 32; off > 0; off >>= 1)
                s += __shfl_xor(s, off, 64);
            if ((tid & 63) == 0) wsum[g][tid >> 6] = s;
        }
        peT[tid] = pe4;                        // unnormalized; 1/Z in epilogue
    }
    __syncthreads();

    // ---------------- pass 2: thread = (d, half-of-K), 64 k each ----------------
    const int dd = tid & (Dc - 1);
    const int kh = tid >> 8;                   // 0..1

    f4 xv = xrow[dd];                          // per-lane, coalesced dwordx4
    f2 xp[2] = {{xv[0], xv[1]}, {xv[2], xv[3]}};
    f2 O[2] = {{0.f, 0.f}, {0.f, 0.f}};
    const f4* PTv = (const f4*)PT;             // [(k>>1)*Dc + d]
    const int j0 = kh * 32;                    // first k-pair index

    #pragma unroll 4
    for (int it = 0; it < 16; ++it) {
        f4 ab = PTv[(j0 + 2 * it + 0) * Dc + dd];   // {c,A} k0,k0+1
        f4 cd = PTv[(j0 + 2 * it + 1) * Dc + dd];   // {c,A} k0+2,k0+3
        const int k0 = (j0 + 2 * it) * 2;
        f4 peA = peT[k0 + 0];                  // LDS b128 broadcast
        f4 peB = peT[k0 + 1];
        f4 peC = peT[k0 + 2];
        f4 peD = peT[k0 + 3];
        #pragma unroll
        for (int p = 0; p < 2; ++p) {
            f2 ep = e2[p], nap = na2[p];
            f2 v0 = fma2(ep, splat2(ab[1]), one2);
            f2 v1 = fma2(ep, splat2(ab[3]), one2);
            f2 v2 = fma2(ep, splat2(cd[1]), one2);
            f2 v3 = fma2(ep, splat2(cd[3]), one2);
            f2 f0 = fma2(nap, splat2(ab[0]), xp[p]);
            f2 f1 = fma2(nap, splat2(ab[2]), xp[p]);
            f2 f2_ = fma2(nap, splat2(cd[0]), xp[p]);
            f2 f3 = fma2(nap, splat2(cd[2]), xp[p]);
            f2 u0 = (f2){peA[2*p], peA[2*p+1]} * f0;
            f2 u1 = (f2){peB[2*p], peB[2*p+1]} * f1;
            f2 u2 = (f2){peC[2*p], peC[2*p+1]} * f2_;
            f2 u3 = (f2){peD[2*p], peD[2*p+1]} * f3;
            f2 d01 = v0 * v1, d23 = v2 * v3;
            f2 n01 = fma2(u1, v0, u0 * v1);
            f2 n23 = fma2(u3, v2, u2 * v3);
            f2 den = d01 * d23;
            f2 num = fma2(n23, d01, n01 * d23);
            O[p] = fma2(num, rcp2(den), O[p]);
        }
    }

    if (kh == 1)
        Opart[dd] = (f4){O[0][0], O[0][1], O[1][0], O[1][1]};
    __syncthreads();

    if (tid < Dc) {
        f4 Ou = Opart[tid];
        #pragma unroll
        for (int p = 0; p < 2; ++p) {
            #pragma unroll
            for (int j = 0; j < 2; ++j) {
                int g = 2 * p + j;
                float Z = wsum[g][0] + wsum[g][1];
                float Osum = O[p][j] + Ou[2 * p + j];
                out[(b0 + g) * Dc + tid] = sg[g] * __builtin_amdgcn_rcpf(Z) * Osum;
            }
        }
    }
}

extern "C" void kernel_launch(void* const* d_in, const int* in_sizes, int n_in,
                              void* d_out, int out_size, void* d_ws, size_t ws_size,
                              hipStream_t stream) {
    const float* x       = (const float*)d_in[0];
    const float* t       = (const float*)d_in[1];
    const float* centers = (const float*)d_in[2];
    const float* stds    = (const float*)d_in[3];
    const float* weights = (const float*)d_in[4];
    float* outp = (float*)d_out;

    float* CA8 = (float*)d_ws;                    // [D/4][K][8]       (256 KB)
    float* PT  = CA8 + Kc * Dc * 2;               // [K/2][D]{c,A,c,A} (256 KB)
    f4*    xt4 = (f4*)(PT + Kc * Dc * 2);         // [B/4][D] 4-row x  (4 MB)

    const int B  = in_sizes[1];                   // 4096
    const int n4 = (B / G) * Dc;                  // 262144 f4 elements

    prep_kernel<<<(Kc * Dc + 255) / 256, 256, 0, stream>>>(centers, stds, CA8, PT);
    prep_x<<<(n4 + 255) / 256, 256, 0, stream>>>(x, xt4, n4);
    score_kernel<<<B / G, 512, 0, stream>>>(xt4, t, weights, CA8, PT, outp);
}